// Round 11
// baseline (112142.432 us; speedup 1.0000x reference)
//
#include <hip/hip_runtime.h>
#include <hip/hip_bf16.h>

#define BB 64
#define TT 1000
#define DD 16
#define HH 1024
#define OO 8

typedef unsigned long long u64;

// ---------------------------------------------------------------------------
// Call-free tanh (no libcall): sign(x) * (1 - 2/(exp2(2*log2e*|x|)+1)).
// ---------------------------------------------------------------------------
__device__ __forceinline__ float fast_tanh(float x) {
    float ax = __builtin_fabsf(x);
    float e  = __builtin_amdgcn_exp2f(ax * 2.88539008177792681f);
    float r  = 1.0f - 2.0f / (e + 1.0f);
    return __builtin_copysignf(r, x);
}

// ===========================================================================
// x-projection precompute: xp[b][t][h] = sum_d x[b][t][d] * Wi2h[h][d]
// ===========================================================================
__global__ __launch_bounds__(256) void xproj_kernel(
    const float* __restrict__ x, const float* __restrict__ Wi2h,
    float* __restrict__ xp)
{
    __shared__ float Wl[1024 * 17];
    for (int i = threadIdx.x; i < 1024 * 16; i += 256)
        Wl[(i >> 4) * 17 + (i & 15)] = Wi2h[i];
    __syncthreads();

    const int nrows = BB * TT;
    for (int row = blockIdx.x; row < nrows; row += gridDim.x) {
        float4 xa = *(const float4*)&x[(size_t)row * 16];
        float4 xb = *(const float4*)&x[(size_t)row * 16 + 4];
        float4 xc = *(const float4*)&x[(size_t)row * 16 + 8];
        float4 xd = *(const float4*)&x[(size_t)row * 16 + 12];
#pragma unroll
        for (int c = 0; c < 4; ++c) {
            int hh = threadIdx.x + 256 * c;
            const float* wr = &Wl[hh * 17];
            float s = xa.x * wr[0]  + xa.y * wr[1]  + xa.z * wr[2]  + xa.w * wr[3]
                    + xb.x * wr[4]  + xb.y * wr[5]  + xb.z * wr[6]  + xb.w * wr[7]
                    + xc.x * wr[8]  + xc.y * wr[9]  + xc.z * wr[10] + xc.w * wr[11]
                    + xd.x * wr[12] + xd.y * wr[13] + xd.z * wr[14] + xd.w * wr[15];
            xp[(size_t)row * HH + hh] = s;
        }
    }
}

// ===========================================================================
// Tier-1: wave-independent RNN. 32 groups x 2 batches; group = 32 blocks
// (256 thr, 4 waves); wave owns 8 j-units x 2 b over FULL k=1024.
// Lane = (j2 = l&1, k32 = l>>1): W/lane = 4 rows x 32 k = 128 VGPR.
// Per step per wave (NO __syncthreads, NO cross-wave anything):
//   poll 128 producer-wave flags (2/lane) -> stage th[2][1024] (8x dwordx4)
//   into wave-private padded LDS -> 256 FMA -> 5-stage shfl_xor butterfly
//   (full k-reduction in-wave) -> lanes 0..15 finalize 16 h, publish th+flag.
// Exchange protocol = proven sc1/LLC relaxed stores + flag gating. Ring WAR
// safety: wave X finalize(t+1) [writes buf p] requires X's poll(t+1)
// observing ALL 128 waves' flags(t+2), each written after that wave's
// stage-reads(t) of buf p. Deadlock-safe only if all 1024 blocks resident:
// gated on hipOccupancy >= 4 host-side.
// ===========================================================================
#define NG   32
#define GBAT 2
#define NBW  1024      // blocks
#define PLNF ((size_t)NG * GBAT * HH)    // TH plane stride (floats)
#define PLNG ((size_t)NG * 128)          // flag plane stride (words)

__global__ __launch_bounds__(256, 4) void rnn_wave(
    const float* __restrict__ h0,    // [64][1024]
    const float* Wh2h,               // [1024][1024]
    const float* __restrict__ xp,    // [64][1000][1024]
    float* __restrict__ out_h,       // [64][1000][1024]
    float* TH,                       // [2][NG][GBAT][1024]
    unsigned* flags)                 // [2][NG][128]
{
    __shared__ __align__(16) float thl[4][GBAT][32][36];   // 36,864 B

    const int tid = threadIdx.x;
    const int w   = tid >> 6;
    const int l   = tid & 63;
    const int bid = blockIdx.x;
    const int bg  = bid & (NG - 1);
    const int pb  = bid >> 5;            // 0..31
    const int Jw  = pb * 32 + w * 8;     // wave's first j-unit
    const int wid = pb * 4 + w;          // producer-wave id in group, 0..127

    const int j2  = l & 1;
    const int k32 = l >> 1;              // 0..31 (bits 1-5 -> butterfly)
    const int Bb  = bg * GBAT;

    // ---- W slice -> VGPRs: rows Jw + j2*4 + jj, cols [k32*32,+32) ----
    float4 w4[4][8];
#pragma unroll
    for (int jj = 0; jj < 4; ++jj) {
        const float* a = &Wh2h[(size_t)(Jw + j2 * 4 + jj) * HH + k32 * 32];
        asm volatile(
            "global_load_dwordx4 %0, %4, off\n\t"
            "global_load_dwordx4 %1, %4, off offset:16\n\t"
            "global_load_dwordx4 %2, %4, off offset:32\n\t"
            "global_load_dwordx4 %3, %4, off offset:48\n\t"
            "s_waitcnt vmcnt(0)"
            : "=&v"(w4[jj][0]), "=&v"(w4[jj][1]), "=&v"(w4[jj][2]), "=&v"(w4[jj][3])
            : "v"(a));
        asm volatile(
            "global_load_dwordx4 %0, %4, off offset:64\n\t"
            "global_load_dwordx4 %1, %4, off offset:80\n\t"
            "global_load_dwordx4 %2, %4, off offset:96\n\t"
            "global_load_dwordx4 %3, %4, off offset:112\n\t"
            "s_waitcnt vmcnt(0)"
            : "=&v"(w4[jj][4]), "=&v"(w4[jj][5]), "=&v"(w4[jj][6]), "=&v"(w4[jj][7])
            : "v"(a));
    }

    // ---- stage maps (t-invariant): lane l, iter i -> global/LDS slots ----
    float* lp[8];
    const float* gp[8];
#pragma unroll
    for (int i = 0; i < 8; ++i) {
        int f = l + 64 * i;              // float4 index in th[2][1024]
        int b = f >> 8, rem = f & 255;
        int ks = rem >> 3, kk = rem & 7;
        lp[i] = &thl[w][b][ks][kk * 4];
        gp[i] = TH + (size_t)bg * GBAT * HH + (size_t)b * HH + ks * 32 + kk * 4;
    }

    // ---- finalize role: lanes 0..15 own (j = Jw + j2*4 + (v&3), b = v>>2) --
    const int v  = l >> 1;               // == k32; valid when l < 16
    const int fjj = v & 3, fbs = v >> 2;
    const int fj = Jw + j2 * 4 + fjj;
    const int fbatch = Bb + fbs;
    float h = 0.f;

    if (l < 16) {
        h = h0[(size_t)fbatch * HH + fj];
        float th0 = fast_tanh(h);
        __hip_atomic_store(&TH[(size_t)bg * GBAT * HH + (size_t)fbs * HH + fj],
                           th0, __ATOMIC_RELAXED, __HIP_MEMORY_SCOPE_AGENT);
    }
    asm volatile("s_waitcnt vmcnt(0)" ::: "memory");
    if (tid % 64 == 0 || l == 0) { }     // (no-op; clarity)
    if (l == 0)
        __hip_atomic_store(&flags[(size_t)bg * 128 + wid], 1u,
                           __ATOMIC_RELAXED, __HIP_MEMORY_SCOPE_AGENT);

    const unsigned* fb0 = flags + (size_t)bg * 128 + l;        // lanes cover 0..63
    const unsigned* fb1 = fb0 + 64;                            // 64..127
    const size_t xh_off = (size_t)fbatch * TT * HH + fj;       // + t*HH

    for (int t = 0; t < TT; ++t) {
        const int p = t & 1;
        const size_t pf = p ? PLNF : 0;      // TH read-plane offset
        const size_t qf = p ? 0 : PLNF;      // TH write-plane offset
        const size_t pg = p ? PLNG : 0;      // flag read-plane
        const size_t qg = p ? 0 : PLNG;      // flag write-plane

        // ---- xp prefetch (consumed in finalize) ----
        float xpv = 0.f;
        if (l < 16) xpv = xp[xh_off + (size_t)t * HH - fj + fj + (size_t)0 + (size_t)t * 0 + 0], // placeholder avoided below
        xpv = xp[(size_t)fbatch * TT * HH + (size_t)t * HH + fj];

        // ---- poll all 128 producer waves (2 flags/lane) ----
        {
            const unsigned tg = (unsigned)(t + 1);
            const unsigned* f0 = fb0 + pg;
            const unsigned* f1 = fb1 + pg;
            for (;;) {
                unsigned a, b;
                asm volatile("global_load_dword %0, %2, off sc0 sc1\n\t"
                             "global_load_dword %1, %3, off sc0 sc1\n\t"
                             "s_waitcnt vmcnt(0)"
                             : "=&v"(a), "=&v"(b)
                             : "v"(f0), "v"(f1) : "memory");
                if (__all((int)((a >= tg) & (b >= tg)))) break;
                __builtin_amdgcn_s_sleep(1);
            }
        }

        // ---- stage th[2][1024] -> wave-private LDS (8 dwordx4/lane) ----
        {
            float4 s0, s1, s2, s3, s4, s5, s6, s7;
            const float* a0 = gp[0] + pf; const float* a1 = gp[1] + pf;
            const float* a2 = gp[2] + pf; const float* a3 = gp[3] + pf;
            const float* a4 = gp[4] + pf; const float* a5 = gp[5] + pf;
            const float* a6 = gp[6] + pf; const float* a7 = gp[7] + pf;
            asm volatile(
                "global_load_dwordx4 %0, %8, off sc0 sc1\n\t"
                "global_load_dwordx4 %1, %9, off sc0 sc1\n\t"
                "global_load_dwordx4 %2, %10, off sc0 sc1\n\t"
                "global_load_dwordx4 %3, %11, off sc0 sc1\n\t"
                "global_load_dwordx4 %4, %12, off sc0 sc1\n\t"
                "global_load_dwordx4 %5, %13, off sc0 sc1\n\t"
                "global_load_dwordx4 %6, %14, off sc0 sc1\n\t"
                "global_load_dwordx4 %7, %15, off sc0 sc1\n\t"
                "s_waitcnt vmcnt(0)"
                : "=&v"(s0), "=&v"(s1), "=&v"(s2), "=&v"(s3),
                  "=&v"(s4), "=&v"(s5), "=&v"(s6), "=&v"(s7)
                : "v"(a0), "v"(a1), "v"(a2), "v"(a3),
                  "v"(a4), "v"(a5), "v"(a6), "v"(a7)
                : "memory");
            *(float4*)lp[0] = s0; *(float4*)lp[1] = s1;
            *(float4*)lp[2] = s2; *(float4*)lp[3] = s3;
            *(float4*)lp[4] = s4; *(float4*)lp[5] = s5;
            *(float4*)lp[6] = s6; *(float4*)lp[7] = s7;
        }

        // ---- compute: 256 FMA over lane's 32-k slice x 4 rows x 2 b ----
        float a00 = 0.f, a10 = 0.f, a20 = 0.f, a30 = 0.f;
        float a01 = 0.f, a11 = 0.f, a21 = 0.f, a31 = 0.f;
        {
            const float* rd0 = &thl[w][0][k32][0];
            const float* rd1 = &thl[w][1][k32][0];
#pragma unroll
            for (int kk = 0; kk < 8; ++kk) {
                float4 t0 = *(const float4*)(rd0 + kk * 4);
                float4 t1 = *(const float4*)(rd1 + kk * 4);
                float4 q0 = w4[0][kk], q1 = w4[1][kk], q2 = w4[2][kk], q3 = w4[3][kk];
                a00 += q0.x * t0.x + q0.y * t0.y + q0.z * t0.z + q0.w * t0.w;
                a10 += q1.x * t0.x + q1.y * t0.y + q1.z * t0.z + q1.w * t0.w;
                a20 += q2.x * t0.x + q2.y * t0.y + q2.z * t0.z + q2.w * t0.w;
                a30 += q3.x * t0.x + q3.y * t0.y + q3.z * t0.z + q3.w * t0.w;
                a01 += q0.x * t1.x + q0.y * t1.y + q0.z * t1.z + q0.w * t1.w;
                a11 += q1.x * t1.x + q1.y * t1.y + q1.z * t1.z + q1.w * t1.w;
                a21 += q2.x * t1.x + q2.y * t1.y + q2.z * t1.z + q2.w * t1.w;
                a31 += q3.x * t1.x + q3.y * t1.y + q3.z * t1.z + q3.w * t1.w;
            }
        }

        // ---- full k-reduction: 5-stage butterfly over bits 1-5 ----
#pragma unroll
        for (int m = 2; m <= 32; m <<= 1) {
            a00 += __shfl_xor(a00, m, 64); a10 += __shfl_xor(a10, m, 64);
            a20 += __shfl_xor(a20, m, 64); a30 += __shfl_xor(a30, m, 64);
            a01 += __shfl_xor(a01, m, 64); a11 += __shfl_xor(a11, m, 64);
            a21 += __shfl_xor(a21, m, 64); a31 += __shfl_xor(a31, m, 64);
        }

        // ---- finalize (lanes 0..15): z select, h update, publish ----
        if (l < 16) {
            float z = (v == 0) ? a00 : (v == 1) ? a10 : (v == 2) ? a20 :
                      (v == 3) ? a30 : (v == 4) ? a01 : (v == 5) ? a11 :
                      (v == 6) ? a21 : a31;
            h = 0.9f * h + 0.1f * (z + xpv);
            float th = fast_tanh(h);
            __hip_atomic_store(
                (float*)((char*)TH + 0) + qf + (size_t)bg * GBAT * HH
                    + (size_t)fbs * HH + fj,
                th, __ATOMIC_RELAXED, __HIP_MEMORY_SCOPE_AGENT);
        }
        asm volatile("s_waitcnt vmcnt(0)" ::: "memory");
        if (l == 0 && t + 1 < TT)
            __hip_atomic_store(flags + qg + (size_t)bg * 128 + wid,
                               (unsigned)(t + 2),
                               __ATOMIC_RELAXED, __HIP_MEMORY_SCOPE_AGENT);
        if (l < 16)
            out_h[(size_t)fbatch * TT * HH + (size_t)t * HH + fj] = h;
    }
}

// ===========================================================================
// Tier-2: round-9 proven kernel (SJ=32, 512 blocks, 2/CU, sc1 protocol).
// ===========================================================================
__global__ __launch_bounds__(512, 4) void rnn_sj32(
    const float* __restrict__ h0, const float* Wh2h,
    const float* __restrict__ xp, float* __restrict__ out_h,
    float* TH, unsigned* flags)
{
    __shared__ __align__(16) float THl[8][4][164];
    __shared__ float SC[2][4][32][9];

    const int tid = threadIdx.x;
    const int w   = tid >> 6;
    const int l   = tid & 63;
    const int bid = blockIdx.x;
    const int bg  = bid & 15;
    const int js  = bid >> 4;

    const int j8 = l & 7;
    const int k8 = l >> 3;
    const int jbase = js * 32 + j8 * 4;
    const int kbase = w * 128 + k8 * 16;

    float4 w4[4][4];
#pragma unroll
    for (int jj = 0; jj < 4; ++jj) {
        const float* a = &Wh2h[(size_t)(jbase + jj) * HH + kbase];
        asm volatile(
            "global_load_dwordx4 %0, %4, off\n\t"
            "global_load_dwordx4 %1, %4, off offset:16\n\t"
            "global_load_dwordx4 %2, %4, off offset:32\n\t"
            "global_load_dwordx4 %3, %4, off offset:48\n\t"
            "s_waitcnt vmcnt(0)"
            : "=&v"(w4[jj][0]), "=&v"(w4[jj][1]), "=&v"(w4[jj][2]), "=&v"(w4[jj][3])
            : "v"(a));
    }

    const int fj = tid & 31, fb = (tid >> 5) & 3;
    float h = 0.f;
    if (tid < 128) {
        h = h0[(size_t)(bg * 4 + fb) * HH + js * 32 + fj];
        float th0 = fast_tanh(h);
        __hip_atomic_store(&TH[((size_t)(0 * 16 + bg) * 4 + fb) * HH + js * 32 + fj],
                           th0, __ATOMIC_RELAXED, __HIP_MEMORY_SCOPE_AGENT);
        asm volatile("s_waitcnt vmcnt(0)" ::: "memory");
        if ((tid & 63) == 0)
            __hip_atomic_store(
                &flags[((size_t)(0 * 16 + bg) * 32 + js) * 16 + (tid >> 6)],
                1u, __ATOMIC_RELAXED, __HIP_MEMORY_SCOPE_AGENT);
    }

    for (int t = 0; t < TT; ++t) {
        const int p = t & 1;
        float xpv = 0.f;
        if (tid < 128)
            xpv = xp[((size_t)(bg * 4 + fb) * TT + t) * HH + js * 32 + fj];
        {
            const unsigned target = (unsigned)(t + 1);
            const unsigned* fa = flags +
                ((size_t)(p * 16 + bg) * 32 + (4 * w + (l >> 1))) * 16 + (l & 1);
            for (;;) {
                unsigned vv = target;
                if (l < 8)
                    vv = __hip_atomic_load(fa, __ATOMIC_RELAXED, __HIP_MEMORY_SCOPE_AGENT);
                if (__all((int)(vv >= target))) break;
                __builtin_amdgcn_s_sleep(1);
            }
        }
        {
            const int b = l & 3, Q0 = l >> 2;
            const float* base = TH + ((size_t)(p * 16 + bg) * 4 + b) * HH + w * 128;
            const float* a0 = base + Q0 * 4;
            const float* a1 = base + (Q0 + 16) * 4;
            float4 v0, v1;
            asm volatile("global_load_dwordx4 %0, %2, off sc0 sc1\n\t"
                         "global_load_dwordx4 %1, %3, off sc0 sc1\n\t"
                         "s_waitcnt vmcnt(0)"
                         : "=&v"(v0), "=&v"(v1)
                         : "v"(a0), "v"(a1) : "memory");
            *(float4*)&THl[w][b][(Q0 >> 2) * 20 + (Q0 & 3) * 4] = v0;
            *(float4*)&THl[w][b][((Q0 + 16) >> 2) * 20 + (Q0 & 3) * 4] = v1;
        }
        asm volatile("s_waitcnt lgkmcnt(0)" ::: "memory");
        __builtin_amdgcn_sched_barrier(0);

        float acc[4][4];
#pragma unroll
        for (int jj = 0; jj < 4; ++jj)
#pragma unroll
            for (int m = 0; m < 4; ++m) acc[jj][m] = 0.f;
#pragma unroll
        for (int kq = 0; kq < 4; ++kq) {
#pragma unroll
            for (int m = 0; m < 4; ++m) {
                float4 tv = *(const float4*)&THl[w][m][k8 * 20 + kq * 4];
#pragma unroll
                for (int jj = 0; jj < 4; ++jj) {
                    acc[jj][m] += w4[jj][kq].x * tv.x;
                    acc[jj][m] += w4[jj][kq].y * tv.y;
                    acc[jj][m] += w4[jj][kq].z * tv.z;
                    acc[jj][m] += w4[jj][kq].w * tv.w;
                }
            }
        }
#pragma unroll
        for (int jj = 0; jj < 4; ++jj)
#pragma unroll
            for (int m = 0; m < 4; ++m) {
                float a = acc[jj][m];
                a += __shfl_xor(a, 8, 64);
                a += __shfl_xor(a, 16, 64);
                a += __shfl_xor(a, 32, 64);
                acc[jj][m] = a;
            }
        if (l < 8) {
#pragma unroll
            for (int m = 0; m < 4; ++m)
#pragma unroll
                for (int jj = 0; jj < 4; ++jj)
                    SC[p][m][l * 4 + jj][w] = acc[jj][m];
        }
        __syncthreads();
        if (tid < 128) {
            float z = 0.f;
#pragma unroll
            for (int ww = 0; ww < 8; ++ww) z += SC[p][fb][fj][ww];
            h = 0.9f * h + 0.1f * (z + xpv);
            float th = fast_tanh(h);
            __hip_atomic_store(
                &TH[((size_t)((p ^ 1) * 16 + bg) * 4 + fb) * HH + js * 32 + fj],
                th, __ATOMIC_RELAXED, __HIP_MEMORY_SCOPE_AGENT);
            asm volatile("s_waitcnt vmcnt(0)" ::: "memory");
            if ((tid & 63) == 0 && t + 1 < TT)
                __hip_atomic_store(
                    &flags[((size_t)((p ^ 1) * 16 + bg) * 32 + js) * 16 + (tid >> 6)],
                    (unsigned)(t + 2), __ATOMIC_RELAXED, __HIP_MEMORY_SCOPE_AGENT);
            out_h[((size_t)(bg * 4 + fb) * TT + t) * HH + js * 32 + fj] = h;
        }
    }
}

// ===========================================================================
// h2o: out[b][t][o] = sum_j tanh(h[b][t][j]) * Wh2o[o][j]
// ===========================================================================
__global__ __launch_bounds__(256) void h2o_kernel(
    const float* __restrict__ hs, const float* __restrict__ Wh2o,
    float* __restrict__ out_o)
{
    __shared__ float Wl[OO * HH];
    for (int i = threadIdx.x; i < OO * HH; i += 256) Wl[i] = Wh2o[i];
    __syncthreads();

    const int w = threadIdx.x >> 6, l = threadIdx.x & 63;
    const size_t nrows = (size_t)BB * TT;
    for (size_t row = (size_t)blockIdx.x * 4 + w; row < nrows; row += (size_t)gridDim.x * 4) {
        const float* hr = hs + row * HH;
        float po[OO] = {0.f};
#pragma unroll
        for (int i = 0; i < 16; ++i) {
            int j = l + 64 * i;
            float th = tanhf(hr[j]);
#pragma unroll
            for (int o = 0; o < OO; ++o) po[o] += th * Wl[o * HH + j];
        }
#pragma unroll
        for (int s = 32; s; s >>= 1)
#pragma unroll
            for (int o = 0; o < OO; ++o) po[o] += __shfl_down(po[o], s, 64);
        if (l == 0) {
#pragma unroll
            for (int o = 0; o < OO; ++o) out_o[row * OO + o] = po[o];
        }
    }
}

// ===========================================================================
// Tier-3 fallback (round-1 style, no workspace needed).
// ===========================================================================
__global__ __launch_bounds__(512) void rnn_fallback(
    const float* __restrict__ x, const float* __restrict__ h0,
    const float* __restrict__ Wi2h, const float* __restrict__ W,
    const float* __restrict__ Wh2o, float* __restrict__ out_o,
    float* __restrict__ out_h)
{
    const int b = blockIdx.x, t0 = threadIdx.x, j0 = 2 * t0;
    const int wave = t0 >> 6, lane = t0 & 63;
    __shared__ float th[HH];
    __shared__ float xs[DD];
    __shared__ float ored[8][OO];
    float wi[2][DD];
#pragma unroll
    for (int d = 0; d < DD; ++d) {
        wi[0][d] = Wi2h[j0 * DD + d];
        wi[1][d] = Wi2h[(j0 + 1) * DD + d];
    }
    float wo[2][OO];
#pragma unroll
    for (int o = 0; o < OO; ++o) {
        wo[0][o] = Wh2o[o * HH + j0];
        wo[1][o] = Wh2o[o * HH + j0 + 1];
    }
    float h[2] = { h0[b * HH + j0], h0[b * HH + j0 + 1] };
    th[j0] = tanhf(h[0]); th[j0 + 1] = tanhf(h[1]);
    if (t0 < DD) xs[t0] = x[(size_t)(b * TT) * DD + t0];
    __syncthreads();
    for (int t = 0; t < TT; ++t) {
        float a0 = 0.f, a1 = 0.f;
        const float* r0 = W + (size_t)j0 * HH;
        const float* r1 = W + (size_t)(j0 + 1) * HH;
#pragma unroll 4
        for (int k = 0; k < HH; k += 4) {
            float4 t4 = *(const float4*)&th[k];
            float4 wA = *(const float4*)(r0 + k);
            float4 wB = *(const float4*)(r1 + k);
            a0 += t4.x * wA.x + t4.y * wA.y + t4.z * wA.z + t4.w * wA.w;
            a1 += t4.x * wB.x + t4.y * wB.y + t4.z * wB.z + t4.w * wB.w;
        }
        float xp0 = 0.f, xp1 = 0.f;
#pragma unroll
        for (int d = 0; d < DD; ++d) { xp0 += xs[d] * wi[0][d]; xp1 += xs[d] * wi[1][d]; }
        h[0] = 0.9f * h[0] + 0.1f * (a0 + xp0);
        h[1] = 0.9f * h[1] + 0.1f * (a1 + xp1);
        float th0 = tanhf(h[0]), th1 = tanhf(h[1]);
        *(float2*)&out_h[((size_t)b * TT + t) * HH + j0] = make_float2(h[0], h[1]);
        float po[OO];
#pragma unroll
        for (int o = 0; o < OO; ++o) po[o] = th0 * wo[0][o] + th1 * wo[1][o];
#pragma unroll
        for (int s = 32; s; s >>= 1)
#pragma unroll
            for (int o = 0; o < OO; ++o) po[o] += __shfl_down(po[o], s, 64);
        __syncthreads();
        if (lane == 0)
#pragma unroll
            for (int o = 0; o < OO; ++o) ored[wave][o] = po[o];
        th[j0] = th0; th[j0 + 1] = th1;
        if (t0 < DD && t + 1 < TT) xs[t0] = x[(size_t)(b * TT + t + 1) * DD + t0];
        __syncthreads();
        if (t0 < OO) {
            float s = 0.f;
#pragma unroll
            for (int ww = 0; ww < 8; ++ww) s += ored[ww][t0];
            out_o[((size_t)b * TT + t) * OO + t0] = s;
        }
    }
}

extern "C" void kernel_launch(void* const* d_in, const int* in_sizes, int n_in,
                              void* d_out, int out_size, void* d_ws, size_t ws_size,
                              hipStream_t stream) {
    const float* x    = (const float*)d_in[0];
    const float* h0   = (const float*)d_in[1];
    const float* Wi2h = (const float*)d_in[2];
    const float* Wh2h = (const float*)d_in[3];
    const float* Wh2o = (const float*)d_in[4];

    float* out_o = (float*)d_out;                    // [64][1000][8]
    float* out_h = out_o + (size_t)BB * TT * OO;     // [64][1000][1024]

    const size_t XP_BYTES  = (size_t)BB * TT * HH * sizeof(float);          // 262 MB
    const size_t THW_BYTES = (size_t)2 * NG * GBAT * HH * sizeof(float);    // 512 KB
    const size_t FGW_BYTES = (size_t)2 * NG * 128 * sizeof(unsigned);       // 32 KB
    const size_t TH2_BYTES = (size_t)2 * 16 * 4 * HH * sizeof(float);       // 512 KB
    const size_t FG2_BYTES = (size_t)2 * 16 * 32 * 16 * sizeof(unsigned);   // 64 KB

    int occW = 0, occ2 = 0;
    (void)hipOccupancyMaxActiveBlocksPerMultiprocessor(
        &occW, reinterpret_cast<const void*>(&rnn_wave), 256, 0);
    (void)hipOccupancyMaxActiveBlocksPerMultiprocessor(
        &occ2, reinterpret_cast<const void*>(&rnn_sj32), 512, 0);

    if (ws_size >= XP_BYTES + THW_BYTES + FGW_BYTES && occW >= 4) {
        float*    xp  = (float*)d_ws;
        float*    TH  = (float*)((char*)d_ws + XP_BYTES);
        unsigned* flg = (unsigned*)((char*)d_ws + XP_BYTES + THW_BYTES);
        hipMemsetAsync(flg, 0, FGW_BYTES, stream);
        xproj_kernel<<<512, 256, 0, stream>>>(x, Wi2h, xp);
        rnn_wave<<<NBW, 256, 0, stream>>>(h0, Wh2h, xp, out_h, TH, flg);
        h2o_kernel<<<2048, 256, 0, stream>>>(out_h, Wh2o, out_o);
    } else if (ws_size >= XP_BYTES + TH2_BYTES + FG2_BYTES && occ2 >= 2) {
        float*    xp  = (float*)d_ws;
        float*    TH  = (float*)((char*)d_ws + XP_BYTES);
        unsigned* flg = (unsigned*)((char*)d_ws + XP_BYTES + TH2_BYTES);
        hipMemsetAsync(flg, 0, FG2_BYTES, stream);
        xproj_kernel<<<512, 256, 0, stream>>>(x, Wi2h, xp);
        rnn_sj32<<<512, 512, 0, stream>>>(h0, Wh2h, xp, out_h, TH, flg);
        h2o_kernel<<<2048, 256, 0, stream>>>(out_h, Wh2o, out_o);
    } else {
        rnn_fallback<<<BB, 512, 0, stream>>>(x, h0, Wi2h, Wh2h, Wh2o, out_o, out_h);
    }
}

// Round 12
// 111996.301 us; speedup vs baseline: 1.0013x; 1.0013x over previous
//
#include <hip/hip_runtime.h>
#include <hip/hip_bf16.h>

#define BB 64
#define TT 1000
#define DD 16
#define HH 1024
#define OO 8

#define NGRP 16         // batch groups
#define GB   4          // batches per group
#define NTH  512

// ---------------------------------------------------------------------------
// Call-free tanh (no libcall): sign(x) * (1 - 2/(exp2(2*log2e*|x|)+1)).
// ---------------------------------------------------------------------------
__device__ __forceinline__ float fast_tanh(float x) {
    float ax = __builtin_fabsf(x);
    float e  = __builtin_amdgcn_exp2f(ax * 2.88539008177792681f);
    float r  = 1.0f - 2.0f / (e + 1.0f);
    return __builtin_copysignf(r, x);
}

// ===========================================================================
// x-projection precompute: xp[b][t][h] = sum_d x[b][t][d] * Wi2h[h][d]
// ===========================================================================
__global__ __launch_bounds__(256) void xproj_kernel(
    const float* __restrict__ x, const float* __restrict__ Wi2h,
    float* __restrict__ xp)
{
    __shared__ float Wl[1024 * 17];
    for (int i = threadIdx.x; i < 1024 * 16; i += 256)
        Wl[(i >> 4) * 17 + (i & 15)] = Wi2h[i];
    __syncthreads();

    const int nrows = BB * TT;
    for (int row = blockIdx.x; row < nrows; row += gridDim.x) {
        float4 xa = *(const float4*)&x[(size_t)row * 16];
        float4 xb = *(const float4*)&x[(size_t)row * 16 + 4];
        float4 xc = *(const float4*)&x[(size_t)row * 16 + 8];
        float4 xd = *(const float4*)&x[(size_t)row * 16 + 12];
#pragma unroll
        for (int c = 0; c < 4; ++c) {
            int hh = threadIdx.x + 256 * c;
            const float* wr = &Wl[hh * 17];
            float s = xa.x * wr[0]  + xa.y * wr[1]  + xa.z * wr[2]  + xa.w * wr[3]
                    + xb.x * wr[4]  + xb.y * wr[5]  + xb.z * wr[6]  + xb.w * wr[7]
                    + xc.x * wr[8]  + xc.y * wr[9]  + xc.z * wr[10] + xc.w * wr[11]
                    + xd.x * wr[12] + xd.y * wr[13] + xd.z * wr[14] + xd.w * wr[15];
            xp[(size_t)row * HH + hh] = s;
        }
    }
}

// ===========================================================================
// Tier-1: round-9 proven structure (SJ=32, 512 blocks, 2/CU, sc1/LLC
// protocol), ONE change: block->(bg,js) mapping decorrelates co-resident
// blocks. bg = (bid&15) ^ ((bid>>5)&15), js = bid>>4 (bijective). Under
// adjacent-pair dispatch (b,b+1) OR wrap-around dispatch (b,b+256), the two
// blocks sharing a CU are in DIFFERENT groups -> phase-independent chains
// hide each other's poll/stage latency.
// Ring/WAR safety unchanged: flags gate every TH read; finalize(t+1)
// happens-after all 32 blocks' stage-reads(t) of the same buffer.
// ===========================================================================
template <int XPRE>
__global__ __launch_bounds__(NTH, 4) void rnn_sj32(
    const float* __restrict__ x,     // [64][1000][16]
    const float* __restrict__ h0,    // [64][1024]
    const float* __restrict__ Wi2h,  // [1024][16]
    const float* Wh2h,               // [1024][1024]
    const float* __restrict__ xp,    // [64][1000][1024] (XPRE=1)
    float* __restrict__ out_h,       // [64][1000][1024]
    float* TH,                       // [2][16][4][1024]
    unsigned* flags)                 // [2][16][32][16] (memset 0 per launch)
{
    __shared__ __align__(16) float THl[8][4][164];      // 21 KB
    __shared__ float SC[2][4][32][9];                   // 9.2 KB [p][b][j][w]
    __shared__ float XS[2][4][20];                      // XPRE=0 only

    const int tid = threadIdx.x;
    const int w   = tid >> 6;
    const int l   = tid & 63;
    const int bid = blockIdx.x;
    const int bg  = (bid & 15) ^ ((bid >> 5) & 15);   // decorrelated group
    const int js  = bid >> 4;                         // 0..31

    const int j8 = l & 7;
    const int k8 = l >> 3;
    const int jbase = js * 32 + j8 * 4;
    const int kbase = w * 128 + k8 * 16;

    // ---- W patch -> VGPR/AGPR file: 16 float4 (opaque asm loads) ----
    float4 w4[4][4];
#pragma unroll
    for (int jj = 0; jj < 4; ++jj) {
        const float* a = &Wh2h[(size_t)(jbase + jj) * HH + kbase];
        asm volatile(
            "global_load_dwordx4 %0, %4, off\n\t"
            "global_load_dwordx4 %1, %4, off offset:16\n\t"
            "global_load_dwordx4 %2, %4, off offset:32\n\t"
            "global_load_dwordx4 %3, %4, off offset:48\n\t"
            "s_waitcnt vmcnt(0)"
            : "=&v"(w4[jj][0]), "=&v"(w4[jj][1]), "=&v"(w4[jj][2]), "=&v"(w4[jj][3])
            : "v"(a));
    }

    // ---- finalize role: tid<128 owns (fj = tid&31, fb = (tid>>5)&3) ----
    const int fj = tid & 31, fb = (tid >> 5) & 3;
    float h = 0.f;
    float wi[DD];
    if (tid < 128) {
        h = h0[(size_t)(bg * GB + fb) * HH + js * 32 + fj];
        if (!XPRE) {
#pragma unroll
            for (int d = 0; d < DD; ++d) wi[d] = Wi2h[(js * 32 + fj) * DD + d];
        }
        float th0 = fast_tanh(h);
        __hip_atomic_store(&TH[((size_t)(0 * NGRP + bg) * GB + fb) * HH + js * 32 + fj],
                           th0, __ATOMIC_RELAXED, __HIP_MEMORY_SCOPE_AGENT);
        asm volatile("s_waitcnt vmcnt(0)" ::: "memory");
        if ((tid & 63) == 0)
            __hip_atomic_store(
                &flags[((size_t)(0 * NGRP + bg) * 32 + js) * 16 + (tid >> 6)],
                1u, __ATOMIC_RELAXED, __HIP_MEMORY_SCOPE_AGENT);
    }

    for (int t = 0; t < TT; ++t) {
        const int p = t & 1;

        // ---- xp prefetch (XPRE): issued before poll, consumed in finalize --
        float xpv = 0.f;
        if (XPRE && tid < 128)
            xpv = xp[((size_t)(bg * GB + fb) * TT + t) * HH + js * 32 + fj];

        // ---- poll: producers pj = 4w + (l>>1), word l&1 (8 lanes) ----
        {
            const unsigned target = (unsigned)(t + 1);
            const unsigned* fa = flags +
                ((size_t)(p * NGRP + bg) * 32 + (4 * w + (l >> 1))) * 16 + (l & 1);
            for (;;) {
                unsigned v = target;
                if (l < 8)
                    v = __hip_atomic_load(fa, __ATOMIC_RELAXED, __HIP_MEMORY_SCOPE_AGENT);
                if (__all((int)(v >= target))) break;
                __builtin_amdgcn_s_sleep(1);
            }
        }

        // ---- stage: lane l -> b = l&3, quads Q0 = l>>2, Q0+16 ----
        {
            const int b = l & 3, Q0 = l >> 2;
            const float* base = TH + ((size_t)(p * NGRP + bg) * GB + b) * HH + w * 128;
            const float* a0 = base + Q0 * 4;
            const float* a1 = base + (Q0 + 16) * 4;
            float4 v0, v1;
            asm volatile("global_load_dwordx4 %0, %2, off sc0 sc1\n\t"
                         "global_load_dwordx4 %1, %3, off sc0 sc1\n\t"
                         "s_waitcnt vmcnt(0)"
                         : "=&v"(v0), "=&v"(v1)
                         : "v"(a0), "v"(a1)
                         : "memory");
            *(float4*)&THl[w][b][(Q0 >> 2) * 20 + (Q0 & 3) * 4] = v0;
            *(float4*)&THl[w][b][((Q0 + 16) >> 2) * 20 + (Q0 & 3) * 4] = v1;
        }
        if (!XPRE && w == 0 && l < 16) {
            int sb2 = l >> 2, dq = (l & 3) * 4;
            float4 v = *(const float4*)&x[((size_t)(bg * GB + sb2) * TT + t) * DD + dq];
            *(float4*)&XS[p][sb2][dq] = v;
        }
        asm volatile("s_waitcnt lgkmcnt(0)" ::: "memory");
        __builtin_amdgcn_sched_barrier(0);

        // ---- compute: acc[jj][m] over lane's 16-k slice x 4 b (256 FMA) ----
        float acc[4][4];
#pragma unroll
        for (int jj = 0; jj < 4; ++jj)
#pragma unroll
            for (int m = 0; m < 4; ++m) acc[jj][m] = 0.f;
#pragma unroll
        for (int kq = 0; kq < 4; ++kq) {
#pragma unroll
            for (int m = 0; m < 4; ++m) {
                float4 tv = *(const float4*)&THl[w][m][k8 * 20 + kq * 4];
#pragma unroll
                for (int jj = 0; jj < 4; ++jj) {
                    acc[jj][m] += w4[jj][kq].x * tv.x;
                    acc[jj][m] += w4[jj][kq].y * tv.y;
                    acc[jj][m] += w4[jj][kq].z * tv.z;
                    acc[jj][m] += w4[jj][kq].w * tv.w;
                }
            }
        }

        // ---- reduce over k8 (xor8/16/32), lanes l<8 publish partials ----
#pragma unroll
        for (int jj = 0; jj < 4; ++jj)
#pragma unroll
            for (int m = 0; m < 4; ++m) {
                float a = acc[jj][m];
                a += __shfl_xor(a, 8, 64);
                a += __shfl_xor(a, 16, 64);
                a += __shfl_xor(a, 32, 64);
                acc[jj][m] = a;
            }
        if (l < 8) {
#pragma unroll
            for (int m = 0; m < 4; ++m)
#pragma unroll
                for (int jj = 0; jj < 4; ++jj)
                    SC[p][m][l * 4 + jj][w] = acc[jj][m];
        }

        __syncthreads();   // the ONE per-step block barrier

        // ---- finalize: h update, TH+flag publish, out_h ----
        if (tid < 128) {
            float z = 0.f;
#pragma unroll
            for (int ww = 0; ww < 8; ++ww) z += SC[p][fb][fj][ww];
            if (!XPRE) {
                xpv = 0.f;
#pragma unroll
                for (int d = 0; d < DD; ++d) xpv += wi[d] * XS[p][fb][d];
            }
            h = 0.9f * h + 0.1f * (z + xpv);
            float th = fast_tanh(h);
            __hip_atomic_store(
                &TH[((size_t)((p ^ 1) * NGRP + bg) * GB + fb) * HH + js * 32 + fj],
                th, __ATOMIC_RELAXED, __HIP_MEMORY_SCOPE_AGENT);
            asm volatile("s_waitcnt vmcnt(0)" ::: "memory");
            if ((tid & 63) == 0 && t + 1 < TT)
                __hip_atomic_store(
                    &flags[((size_t)((p ^ 1) * NGRP + bg) * 32 + js) * 16 + (tid >> 6)],
                    (unsigned)(t + 2), __ATOMIC_RELAXED, __HIP_MEMORY_SCOPE_AGENT);
            out_h[((size_t)(bg * GB + fb) * TT + t) * HH + js * 32 + fj] = h;
        }
    }
}

// ===========================================================================
// h2o: out[b][t][o] = sum_j tanh(h[b][t][j]) * Wh2o[o][j]
// ===========================================================================
__global__ __launch_bounds__(256) void h2o_kernel(
    const float* __restrict__ hs, const float* __restrict__ Wh2o,
    float* __restrict__ out_o)
{
    __shared__ float Wl[OO * HH];
    for (int i = threadIdx.x; i < OO * HH; i += 256) Wl[i] = Wh2o[i];
    __syncthreads();

    const int w = threadIdx.x >> 6, l = threadIdx.x & 63;
    const size_t nrows = (size_t)BB * TT;
    for (size_t row = (size_t)blockIdx.x * 4 + w; row < nrows; row += (size_t)gridDim.x * 4) {
        const float* hr = hs + row * HH;
        float po[OO] = {0.f};
#pragma unroll
        for (int i = 0; i < 16; ++i) {
            int j = l + 64 * i;
            float th = tanhf(hr[j]);
#pragma unroll
            for (int o = 0; o < OO; ++o) po[o] += th * Wl[o * HH + j];
        }
#pragma unroll
        for (int s = 32; s; s >>= 1)
#pragma unroll
            for (int o = 0; o < OO; ++o) po[o] += __shfl_down(po[o], s, 64);
        if (l == 0) {
#pragma unroll
            for (int o = 0; o < OO; ++o) out_o[row * OO + o] = po[o];
        }
    }
}

// ===========================================================================
// Tier-3 fallback (round-1 style, no workspace needed).
// ===========================================================================
__global__ __launch_bounds__(512) void rnn_fallback(
    const float* __restrict__ x, const float* __restrict__ h0,
    const float* __restrict__ Wi2h, const float* __restrict__ W,
    const float* __restrict__ Wh2o, float* __restrict__ out_o,
    float* __restrict__ out_h)
{
    const int b = blockIdx.x, t0 = threadIdx.x, j0 = 2 * t0;
    const int wave = t0 >> 6, lane = t0 & 63;
    __shared__ float th[HH];
    __shared__ float xs[DD];
    __shared__ float ored[8][OO];
    float wi[2][DD];
#pragma unroll
    for (int d = 0; d < DD; ++d) {
        wi[0][d] = Wi2h[j0 * DD + d];
        wi[1][d] = Wi2h[(j0 + 1) * DD + d];
    }
    float wo[2][OO];
#pragma unroll
    for (int o = 0; o < OO; ++o) {
        wo[0][o] = Wh2o[o * HH + j0];
        wo[1][o] = Wh2o[o * HH + j0 + 1];
    }
    float h[2] = { h0[b * HH + j0], h0[b * HH + j0 + 1] };
    th[j0] = tanhf(h[0]); th[j0 + 1] = tanhf(h[1]);
    if (t0 < DD) xs[t0] = x[(size_t)(b * TT) * DD + t0];
    __syncthreads();
    for (int t = 0; t < TT; ++t) {
        float a0 = 0.f, a1 = 0.f;
        const float* r0 = W + (size_t)j0 * HH;
        const float* r1 = W + (size_t)(j0 + 1) * HH;
#pragma unroll 4
        for (int k = 0; k < HH; k += 4) {
            float4 t4 = *(const float4*)&th[k];
            float4 wA = *(const float4*)(r0 + k);
            float4 wB = *(const float4*)(r1 + k);
            a0 += t4.x * wA.x + t4.y * wA.y + t4.z * wA.z + t4.w * wA.w;
            a1 += t4.x * wB.x + t4.y * wB.y + t4.z * wB.z + t4.w * wB.w;
        }
        float xp0 = 0.f, xp1 = 0.f;
#pragma unroll
        for (int d = 0; d < DD; ++d) { xp0 += xs[d] * wi[0][d]; xp1 += xs[d] * wi[1][d]; }
        h[0] = 0.9f * h[0] + 0.1f * (a0 + xp0);
        h[1] = 0.9f * h[1] + 0.1f * (a1 + xp1);
        float th0 = tanhf(h[0]), th1 = tanhf(h[1]);
        *(float2*)&out_h[((size_t)b * TT + t) * HH + j0] = make_float2(h[0], h[1]);
        float po[OO];
#pragma unroll
        for (int o = 0; o < OO; ++o) po[o] = th0 * wo[0][o] + th1 * wo[1][o];
#pragma unroll
        for (int s = 32; s; s >>= 1)
#pragma unroll
            for (int o = 0; o < OO; ++o) po[o] += __shfl_down(po[o], s, 64);
        __syncthreads();
        if (lane == 0)
#pragma unroll
            for (int o = 0; o < OO; ++o) ored[wave][o] = po[o];
        th[j0] = th0; th[j0 + 1] = th1;
        if (t0 < DD && t + 1 < TT) xs[t0] = x[(size_t)(b * TT + t + 1) * DD + t0];
        __syncthreads();
        if (t0 < OO) {
            float s = 0.f;
#pragma unroll
            for (int ww = 0; ww < 8; ++ww) s += ored[ww][t0];
            out_o[((size_t)b * TT + t) * OO + t0] = s;
        }
    }
}

extern "C" void kernel_launch(void* const* d_in, const int* in_sizes, int n_in,
                              void* d_out, int out_size, void* d_ws, size_t ws_size,
                              hipStream_t stream) {
    const float* x    = (const float*)d_in[0];
    const float* h0   = (const float*)d_in[1];
    const float* Wi2h = (const float*)d_in[2];
    const float* Wh2h = (const float*)d_in[3];
    const float* Wh2o = (const float*)d_in[4];

    float* out_o = (float*)d_out;                    // [64][1000][8]
    float* out_h = out_o + (size_t)BB * TT * OO;     // [64][1000][1024]

    const size_t XP_BYTES   = (size_t)BB * TT * HH * sizeof(float);            // 262 MB
    const size_t TH_BYTES   = (size_t)2 * NGRP * GB * HH * sizeof(float);      // 512 KB
    const size_t FLG_BYTES  = (size_t)2 * NGRP * 32 * 16 * sizeof(unsigned);   // 64 KB

    int occ1 = 0, occ0 = 0;
    (void)hipOccupancyMaxActiveBlocksPerMultiprocessor(
        &occ1, reinterpret_cast<const void*>(&rnn_sj32<1>), NTH, 0);
    (void)hipOccupancyMaxActiveBlocksPerMultiprocessor(
        &occ0, reinterpret_cast<const void*>(&rnn_sj32<0>), NTH, 0);

    if (ws_size >= XP_BYTES + TH_BYTES + FLG_BYTES && occ1 >= 2) {
        float*    xp  = (float*)d_ws;
        float*    TH  = (float*)((char*)d_ws + XP_BYTES);
        unsigned* flg = (unsigned*)((char*)d_ws + XP_BYTES + TH_BYTES);
        hipMemsetAsync(flg, 0, FLG_BYTES, stream);
        xproj_kernel<<<512, 256, 0, stream>>>(x, Wi2h, xp);
        rnn_sj32<1><<<512, NTH, 0, stream>>>(x, h0, Wi2h, Wh2h, xp, out_h, TH, flg);
        h2o_kernel<<<2048, 256, 0, stream>>>(out_h, Wh2o, out_o);
    } else if (ws_size >= TH_BYTES + FLG_BYTES && occ0 >= 2) {
        float*    TH  = (float*)d_ws;
        unsigned* flg = (unsigned*)((char*)d_ws + TH_BYTES);
        hipMemsetAsync(flg, 0, FLG_BYTES, stream);
        rnn_sj32<0><<<512, NTH, 0, stream>>>(x, h0, Wi2h, Wh2h, (const float*)d_ws,
                                             out_h, TH, flg);
        h2o_kernel<<<2048, 256, 0, stream>>>(out_h, Wh2o, out_o);
    } else {
        rnn_fallback<<<BB, 512, 0, stream>>>(x, h0, Wi2h, Wh2h, Wh2o, out_o, out_h);
    }
}

// Round 13
// 4920.777 us; speedup vs baseline: 22.7896x; 22.7599x over previous
//
#include <hip/hip_runtime.h>
#include <hip/hip_bf16.h>

#define BB 64
#define TT 1000
#define DD 16
#define HH 1024
#define OO 8

#define NGRP 16         // batch groups
#define GB   4          // batches per group
#define NTH  512

typedef unsigned long long u64;

// ---------------------------------------------------------------------------
// Call-free tanh (no libcall): sign(x) * (1 - 2/(exp2(2*log2e*|x|)+1)).
// ---------------------------------------------------------------------------
__device__ __forceinline__ float fast_tanh(float x) {
    float ax = __builtin_fabsf(x);
    float e  = __builtin_amdgcn_exp2f(ax * 2.88539008177792681f); // 2*log2(e)
    float r  = 1.0f - 2.0f / (e + 1.0f);
    return __builtin_copysignf(r, x);
}

// ===========================================================================
// x-projection precompute: xp[b][t][h] = sum_d x[b][t][d] * Wi2h[h][d]
// ===========================================================================
__global__ __launch_bounds__(256) void xproj_kernel(
    const float* __restrict__ x,     // [64][1000][16]
    const float* __restrict__ Wi2h,  // [1024][16]
    float* __restrict__ xp)          // [64][1000][1024]
{
    __shared__ float Wl[1024 * 17];  // [h][d] padded 16->17 (bank-safe)
    for (int i = threadIdx.x; i < 1024 * 16; i += 256)
        Wl[(i >> 4) * 17 + (i & 15)] = Wi2h[i];
    __syncthreads();

    const int nrows = BB * TT;
    for (int row = blockIdx.x; row < nrows; row += gridDim.x) {
        float4 xa = *(const float4*)&x[(size_t)row * 16];
        float4 xb = *(const float4*)&x[(size_t)row * 16 + 4];
        float4 xc = *(const float4*)&x[(size_t)row * 16 + 8];
        float4 xd = *(const float4*)&x[(size_t)row * 16 + 12];
#pragma unroll
        for (int c = 0; c < 4; ++c) {
            int hh = threadIdx.x + 256 * c;
            const float* wr = &Wl[hh * 17];
            float s = xa.x * wr[0]  + xa.y * wr[1]  + xa.z * wr[2]  + xa.w * wr[3]
                    + xb.x * wr[4]  + xb.y * wr[5]  + xb.z * wr[6]  + xb.w * wr[7]
                    + xc.x * wr[8]  + xc.y * wr[9]  + xc.z * wr[10] + xc.w * wr[11]
                    + xd.x * wr[12] + xd.y * wr[13] + xd.z * wr[14] + xd.w * wr[15];
            xp[(size_t)row * HH + hh] = s;
        }
    }
}

// ===========================================================================
// Tier-1: SJ=32, 512 blocks (2/CU). Round-9 champion, verbatim.
// Block (bg, js): batches [bg*4,+4), units [js*32,+32).
// Wave w: k-stripe [w*128,+128). Lane = j8 (l&7) x k8 (l>>3):
//   4 j x 16 k x 4 b = 256 FMA/lane/step; W/lane = 64 floats (16 float4).
// th exchange: TH[2][16][4][1024] relaxed-agent (sc1/LLC) stores + 2 flag
// words per (grp, js); consumers poll 8 lanes then LLC-direct sc0 sc1
// stripe loads. Ring WAR safety: each block's 8 waves poll producers
// {4w..4w+3} = ALL 32 blocks of the group, so finalize(t+1) happens-after
// every block's stage-reads(t). One __syncthreads per step.
// ===========================================================================
template <int XPRE>
__global__ __launch_bounds__(NTH, 4) void rnn_sj32(
    const float* __restrict__ x,     // [64][1000][16]
    const float* __restrict__ h0,    // [64][1024]
    const float* __restrict__ Wi2h,  // [1024][16]
    const float* Wh2h,               // [1024][1024]
    const float* __restrict__ xp,    // [64][1000][1024] (XPRE=1)
    float* __restrict__ out_h,       // [64][1000][1024]
    float* TH,                       // [2][16][4][1024]
    unsigned* flags)                 // [2][16][32][16] (memset 0 per launch)
{
    __shared__ __align__(16) float THl[8][4][164];      // 21 KB
    __shared__ float SC[2][4][32][9];                   // 9.2 KB [p][b][j][w]
    __shared__ float XS[2][4][20];                      // XPRE=0 only

    const int tid = threadIdx.x;
    const int w   = tid >> 6;
    const int l   = tid & 63;
    const int bid = blockIdx.x;
    const int bg  = bid & (NGRP - 1);
    const int js  = bid >> 4;         // 0..31

    const int j8 = l & 7;
    const int k8 = l >> 3;            // 0..7 (bits 3-5 -> xor8/16/32 reduce)
    const int jbase = js * 32 + j8 * 4;
    const int kbase = w * 128 + k8 * 16;

    // ---- W patch -> VGPR/AGPR file: 16 float4 (opaque asm loads) ----
    float4 w4[4][4];
#pragma unroll
    for (int jj = 0; jj < 4; ++jj) {
        const float* a = &Wh2h[(size_t)(jbase + jj) * HH + kbase];
        asm volatile(
            "global_load_dwordx4 %0, %4, off\n\t"
            "global_load_dwordx4 %1, %4, off offset:16\n\t"
            "global_load_dwordx4 %2, %4, off offset:32\n\t"
            "global_load_dwordx4 %3, %4, off offset:48\n\t"
            "s_waitcnt vmcnt(0)"
            : "=&v"(w4[jj][0]), "=&v"(w4[jj][1]), "=&v"(w4[jj][2]), "=&v"(w4[jj][3])
            : "v"(a));
    }

    // ---- finalize role: tid<128 owns (fj = tid&31, fb = (tid>>5)&3) ----
    const int fj = tid & 31, fb = (tid >> 5) & 3;
    float h = 0.f;
    float wi[DD];
    if (tid < 128) {
        h = h0[(size_t)(bg * GB + fb) * HH + js * 32 + fj];
        if (!XPRE) {
#pragma unroll
            for (int d = 0; d < DD; ++d) wi[d] = Wi2h[(js * 32 + fj) * DD + d];
        }
        float th0 = fast_tanh(h);
        __hip_atomic_store(&TH[((size_t)(0 * NGRP + bg) * GB + fb) * HH + js * 32 + fj],
                           th0, __ATOMIC_RELAXED, __HIP_MEMORY_SCOPE_AGENT);
        asm volatile("s_waitcnt vmcnt(0)" ::: "memory");
        if ((tid & 63) == 0)
            __hip_atomic_store(
                &flags[((size_t)(0 * NGRP + bg) * 32 + js) * 16 + (tid >> 6)],
                1u, __ATOMIC_RELAXED, __HIP_MEMORY_SCOPE_AGENT);
    }

    for (int t = 0; t < TT; ++t) {
        const int p = t & 1;

        // ---- xp prefetch (XPRE): issued before poll, consumed in finalize --
        float xpv = 0.f;
        if (XPRE && tid < 128)
            xpv = xp[((size_t)(bg * GB + fb) * TT + t) * HH + js * 32 + fj];

        // ---- poll: producers pj = 4w + (l>>1), word l&1 (8 lanes) ----
        {
            const unsigned target = (unsigned)(t + 1);
            const unsigned* fa = flags +
                ((size_t)(p * NGRP + bg) * 32 + (4 * w + (l >> 1))) * 16 + (l & 1);
            for (;;) {
                unsigned v = target;
                if (l < 8)
                    v = __hip_atomic_load(fa, __ATOMIC_RELAXED, __HIP_MEMORY_SCOPE_AGENT);
                if (__all((int)(v >= target))) break;
                __builtin_amdgcn_s_sleep(1);
            }
        }

        // ---- stage: lane l -> b = l&3, quads Q0 = l>>2, Q0+16 ----
        {
            const int b = l & 3, Q0 = l >> 2;
            const float* base = TH + ((size_t)(p * NGRP + bg) * GB + b) * HH + w * 128;
            const float* a0 = base + Q0 * 4;
            const float* a1 = base + (Q0 + 16) * 4;
            float4 v0, v1;
            asm volatile("global_load_dwordx4 %0, %2, off sc0 sc1\n\t"
                         "global_load_dwordx4 %1, %3, off sc0 sc1\n\t"
                         "s_waitcnt vmcnt(0)"
                         : "=&v"(v0), "=&v"(v1)
                         : "v"(a0), "v"(a1)
                         : "memory");
            *(float4*)&THl[w][b][(Q0 >> 2) * 20 + (Q0 & 3) * 4] = v0;
            *(float4*)&THl[w][b][((Q0 + 16) >> 2) * 20 + (Q0 & 3) * 4] = v1;
        }
        if (!XPRE && w == 0 && l < 16) {
            int sb2 = l >> 2, dq = (l & 3) * 4;
            float4 v = *(const float4*)&x[((size_t)(bg * GB + sb2) * TT + t) * DD + dq];
            *(float4*)&XS[p][sb2][dq] = v;
        }
        asm volatile("s_waitcnt lgkmcnt(0)" ::: "memory");
        __builtin_amdgcn_sched_barrier(0);

        // ---- compute: acc[jj][m] over lane's 16-k slice x 4 b (256 FMA) ----
        float acc[4][4];
#pragma unroll
        for (int jj = 0; jj < 4; ++jj)
#pragma unroll
            for (int m = 0; m < 4; ++m) acc[jj][m] = 0.f;
#pragma unroll
        for (int kq = 0; kq < 4; ++kq) {
#pragma unroll
            for (int m = 0; m < 4; ++m) {
                float4 tv = *(const float4*)&THl[w][m][k8 * 20 + kq * 4];
#pragma unroll
                for (int jj = 0; jj < 4; ++jj) {
                    acc[jj][m] += w4[jj][kq].x * tv.x;
                    acc[jj][m] += w4[jj][kq].y * tv.y;
                    acc[jj][m] += w4[jj][kq].z * tv.z;
                    acc[jj][m] += w4[jj][kq].w * tv.w;
                }
            }
        }

        // ---- reduce over k8 (xor8/16/32), lanes l<8 publish partials ----
#pragma unroll
        for (int jj = 0; jj < 4; ++jj)
#pragma unroll
            for (int m = 0; m < 4; ++m) {
                float a = acc[jj][m];
                a += __shfl_xor(a, 8, 64);
                a += __shfl_xor(a, 16, 64);
                a += __shfl_xor(a, 32, 64);
                acc[jj][m] = a;
            }
        if (l < 8) {
#pragma unroll
            for (int m = 0; m < 4; ++m)
#pragma unroll
                for (int jj = 0; jj < 4; ++jj)
                    SC[p][m][l * 4 + jj][w] = acc[jj][m];
        }

        __syncthreads();   // the ONE per-step block barrier

        // ---- finalize: h update, TH+flag publish, out_h ----
        if (tid < 128) {
            float z = 0.f;
#pragma unroll
            for (int ww = 0; ww < 8; ++ww) z += SC[p][fb][fj][ww];
            if (!XPRE) {
                xpv = 0.f;
#pragma unroll
                for (int d = 0; d < DD; ++d) xpv += wi[d] * XS[p][fb][d];
            }
            h = 0.9f * h + 0.1f * (z + xpv);
            float th = fast_tanh(h);
            __hip_atomic_store(
                &TH[((size_t)((p ^ 1) * NGRP + bg) * GB + fb) * HH + js * 32 + fj],
                th, __ATOMIC_RELAXED, __HIP_MEMORY_SCOPE_AGENT);
            asm volatile("s_waitcnt vmcnt(0)" ::: "memory");
            if ((tid & 63) == 0 && t + 1 < TT)
                __hip_atomic_store(
                    &flags[((size_t)((p ^ 1) * NGRP + bg) * 32 + js) * 16 + (tid >> 6)],
                    (unsigned)(t + 2), __ATOMIC_RELAXED, __HIP_MEMORY_SCOPE_AGENT);
            out_h[((size_t)(bg * GB + fb) * TT + t) * HH + js * 32 + fj] = h;
        }
    }
}

// ===========================================================================
// Tier-2: SJ=64, 256 blocks, 1/CU (round-7 structure), fast_tanh.
// ===========================================================================
__global__ __launch_bounds__(NTH, 1) void rnn_coop_t2(
    const float* __restrict__ x, const float* __restrict__ h0,
    const float* __restrict__ Wi2h, const float* Wh2h,
    float* __restrict__ out_h, float* TH, unsigned* flags)
{
    __shared__ __align__(16) float THl[8][4][GB][36];
    __shared__ float SC[2][GB][64][9];
    __shared__ float XS[2][GB][20];

    const int tid = threadIdx.x;
    const int w   = tid >> 6;
    const int l   = tid & 63;
    const int bid = blockIdx.x;
    const int bg  = bid & (NGRP - 1);
    const int js  = bid >> 4;         // 0..15

    const int j16 = l & 15;
    const int k4  = l >> 4;
    const int jbase = js * 64 + j16 * 4;
    const int kbase = w * 128 + k4 * 32;

    float4 w4[4][8];
#pragma unroll
    for (int jj = 0; jj < 4; ++jj) {
        const float* a = &Wh2h[(size_t)(jbase + jj) * HH + kbase];
        asm volatile(
            "global_load_dwordx4 %0, %8, off\n\t"
            "global_load_dwordx4 %1, %8, off offset:16\n\t"
            "global_load_dwordx4 %2, %8, off offset:32\n\t"
            "global_load_dwordx4 %3, %8, off offset:48\n\t"
            "global_load_dwordx4 %4, %8, off offset:64\n\t"
            "global_load_dwordx4 %5, %8, off offset:80\n\t"
            "global_load_dwordx4 %6, %8, off offset:96\n\t"
            "global_load_dwordx4 %7, %8, off offset:112\n\t"
            "s_waitcnt vmcnt(0)"
            : "=&v"(w4[jj][0]), "=&v"(w4[jj][1]), "=&v"(w4[jj][2]), "=&v"(w4[jj][3]),
              "=&v"(w4[jj][4]), "=&v"(w4[jj][5]), "=&v"(w4[jj][6]), "=&v"(w4[jj][7])
            : "v"(a));
    }

    const int fb = tid >> 6, fj = tid & 63;
    float h = 0.f;
    float wi[DD];
    if (tid < 256) {
        h = h0[(size_t)(bg * GB + fb) * HH + js * 64 + fj];
#pragma unroll
        for (int d = 0; d < DD; ++d) wi[d] = Wi2h[(js * 64 + fj) * DD + d];
        float th0 = fast_tanh(h);
        __hip_atomic_store(&TH[((size_t)(0 * NGRP + bg) * GB + fb) * HH + js * 64 + fj],
                           th0, __ATOMIC_RELAXED, __HIP_MEMORY_SCOPE_AGENT);
        asm volatile("s_waitcnt vmcnt(0)" ::: "memory");
        if (l == 0)
            __hip_atomic_store(&flags[((size_t)(0 * NGRP + bg) * 16 + js) * 16 + fb],
                               1u, __ATOMIC_RELAXED, __HIP_MEMORY_SCOPE_AGENT);
    }

    for (int t = 0; t < TT; ++t) {
        const int p = t & 1;
        {
            const unsigned target = (unsigned)(t + 1);
            const unsigned* fa = flags +
                ((size_t)(p * NGRP + bg) * 16 + (2 * w + (l >> 2))) * 16 + (l & 3);
            for (;;) {
                unsigned v = target;
                if (l < 8)
                    v = __hip_atomic_load(fa, __ATOMIC_RELAXED, __HIP_MEMORY_SCOPE_AGENT);
                if (__all((int)(v >= target))) break;
                __builtin_amdgcn_s_sleep(1);
            }
        }
        {
            const int sb = l >> 4, sq = l & 15;
            const float* base = TH + ((size_t)(p * NGRP + bg) * GB + sb) * HH + w * 128;
            const float* a0 = base + sq * 4;
            const float* a1 = base + (sq + 16) * 4;
            float4 v0, v1;
            asm volatile("global_load_dwordx4 %0, %2, off sc0 sc1\n\t"
                         "global_load_dwordx4 %1, %3, off sc0 sc1\n\t"
                         "s_waitcnt vmcnt(0)"
                         : "=&v"(v0), "=&v"(v1)
                         : "v"(a0), "v"(a1)
                         : "memory");
            int k40 = sq >> 3,        kk0 = (sq & 7) ^ k40;
            int k41 = (sq + 16) >> 3, kk1 = (sq & 7) ^ k41;
            *(float4*)&THl[w][k40][sb][kk0 * 4] = v0;
            *(float4*)&THl[w][k41][sb][kk1 * 4] = v1;
        }
        if (w == 0 && l < 16) {
            int sb2 = l >> 2, dq = (l & 3) * 4;
            float4 v = *(const float4*)&x[((size_t)(bg * GB + sb2) * TT + t) * DD + dq];
            *(float4*)&XS[p][sb2][dq] = v;
        }
        asm volatile("s_waitcnt lgkmcnt(0)" ::: "memory");
        __builtin_amdgcn_sched_barrier(0);

        float acc[4][4];
#pragma unroll
        for (int jj = 0; jj < 4; ++jj)
#pragma unroll
            for (int m = 0; m < 4; ++m) acc[jj][m] = 0.f;
#pragma unroll
        for (int kq = 0; kq < 8; ++kq) {
            const int kks = (kq ^ k4) * 4;
#pragma unroll
            for (int m = 0; m < 4; ++m) {
                float4 tv = *(const float4*)&THl[w][k4][m][kks];
#pragma unroll
                for (int jj = 0; jj < 4; ++jj) {
                    acc[jj][m] += w4[jj][kq].x * tv.x;
                    acc[jj][m] += w4[jj][kq].y * tv.y;
                    acc[jj][m] += w4[jj][kq].z * tv.z;
                    acc[jj][m] += w4[jj][kq].w * tv.w;
                }
            }
        }
#pragma unroll
        for (int jj = 0; jj < 4; ++jj)
#pragma unroll
            for (int m = 0; m < 4; ++m) {
                float a = acc[jj][m];
                a += __shfl_xor(a, 16, 64);
                a += __shfl_xor(a, 32, 64);
                acc[jj][m] = a;
            }
        if (k4 == 0) {
#pragma unroll
            for (int m = 0; m < 4; ++m)
#pragma unroll
                for (int jj = 0; jj < 4; ++jj)
                    SC[p][m][j16 * 4 + jj][w] = acc[jj][m];
        }
        __syncthreads();
        if (tid < 256) {
            float z = 0.f;
#pragma unroll
            for (int ww = 0; ww < 8; ++ww) z += SC[p][fb][fj][ww];
            float xpv = 0.f;
#pragma unroll
            for (int d = 0; d < DD; ++d) xpv += wi[d] * XS[p][fb][d];
            h = 0.9f * h + 0.1f * (z + xpv);
            float th = fast_tanh(h);
            __hip_atomic_store(
                &TH[((size_t)((p ^ 1) * NGRP + bg) * GB + fb) * HH + js * 64 + fj],
                th, __ATOMIC_RELAXED, __HIP_MEMORY_SCOPE_AGENT);
            asm volatile("s_waitcnt vmcnt(0)" ::: "memory");
            if (l == 0 && t + 1 < TT)
                __hip_atomic_store(
                    &flags[((size_t)((p ^ 1) * NGRP + bg) * 16 + js) * 16 + fb],
                    (unsigned)(t + 2), __ATOMIC_RELAXED, __HIP_MEMORY_SCOPE_AGENT);
            out_h[((size_t)(bg * GB + fb) * TT + t) * HH + js * 64 + fj] = h;
        }
    }
}

// ===========================================================================
// h2o: out[b][t][o] = sum_j tanh(h[b][t][j]) * Wh2o[o][j]
// ===========================================================================
__global__ __launch_bounds__(256) void h2o_kernel(
    const float* __restrict__ hs, const float* __restrict__ Wh2o,
    float* __restrict__ out_o)
{
    __shared__ float Wl[OO * HH];
    for (int i = threadIdx.x; i < OO * HH; i += 256) Wl[i] = Wh2o[i];
    __syncthreads();

    const int w = threadIdx.x >> 6, l = threadIdx.x & 63;
    const size_t nrows = (size_t)BB * TT;
    for (size_t row = (size_t)blockIdx.x * 4 + w; row < nrows; row += (size_t)gridDim.x * 4) {
        const float* hr = hs + row * HH;
        float po[OO] = {0.f};
#pragma unroll
        for (int i = 0; i < 16; ++i) {
            int j = l + 64 * i;
            float th = tanhf(hr[j]);
#pragma unroll
            for (int o = 0; o < OO; ++o) po[o] += th * Wl[o * HH + j];
        }
#pragma unroll
        for (int s = 32; s; s >>= 1)
#pragma unroll
            for (int o = 0; o < OO; ++o) po[o] += __shfl_down(po[o], s, 64);
        if (l == 0) {
#pragma unroll
            for (int o = 0; o < OO; ++o) out_o[row * OO + o] = po[o];
        }
    }
}

// ===========================================================================
// Tier-3 fallback (round-1 style, no workspace needed).
// ===========================================================================
__global__ __launch_bounds__(512) void rnn_fallback(
    const float* __restrict__ x, const float* __restrict__ h0,
    const float* __restrict__ Wi2h, const float* __restrict__ W,
    const float* __restrict__ Wh2o, float* __restrict__ out_o,
    float* __restrict__ out_h)
{
    const int b = blockIdx.x, t0 = threadIdx.x, j0 = 2 * t0;
    const int wave = t0 >> 6, lane = t0 & 63;
    __shared__ float th[HH];
    __shared__ float xs[DD];
    __shared__ float ored[8][OO];
    float wi[2][DD];
#pragma unroll
    for (int d = 0; d < DD; ++d) {
        wi[0][d] = Wi2h[j0 * DD + d];
        wi[1][d] = Wi2h[(j0 + 1) * DD + d];
    }
    float wo[2][OO];
#pragma unroll
    for (int o = 0; o < OO; ++o) {
        wo[0][o] = Wh2o[o * HH + j0];
        wo[1][o] = Wh2o[o * HH + j0 + 1];
    }
    float h[2] = { h0[b * HH + j0], h0[b * HH + j0 + 1] };
    th[j0] = tanhf(h[0]); th[j0 + 1] = tanhf(h[1]);
    if (t0 < DD) xs[t0] = x[(size_t)(b * TT) * DD + t0];
    __syncthreads();
    for (int t = 0; t < TT; ++t) {
        float a0 = 0.f, a1 = 0.f;
        const float* r0 = W + (size_t)j0 * HH;
        const float* r1 = W + (size_t)(j0 + 1) * HH;
#pragma unroll 4
        for (int k = 0; k < HH; k += 4) {
            float4 t4 = *(const float4*)&th[k];
            float4 wA = *(const float4*)(r0 + k);
            float4 wB = *(const float4*)(r1 + k);
            a0 += t4.x * wA.x + t4.y * wA.y + t4.z * wA.z + t4.w * wA.w;
            a1 += t4.x * wB.x + t4.y * wB.y + t4.z * wB.z + t4.w * wB.w;
        }
        float xp0 = 0.f, xp1 = 0.f;
#pragma unroll
        for (int d = 0; d < DD; ++d) { xp0 += xs[d] * wi[0][d]; xp1 += xs[d] * wi[1][d]; }
        h[0] = 0.9f * h[0] + 0.1f * (a0 + xp0);
        h[1] = 0.9f * h[1] + 0.1f * (a1 + xp1);
        float th0 = tanhf(h[0]), th1 = tanhf(h[1]);
        *(float2*)&out_h[((size_t)b * TT + t) * HH + j0] = make_float2(h[0], h[1]);
        float po[OO];
#pragma unroll
        for (int o = 0; o < OO; ++o) po[o] = th0 * wo[0][o] + th1 * wo[1][o];
#pragma unroll
        for (int s = 32; s; s >>= 1)
#pragma unroll
            for (int o = 0; o < OO; ++o) po[o] += __shfl_down(po[o], s, 64);
        __syncthreads();
        if (lane == 0)
#pragma unroll
            for (int o = 0; o < OO; ++o) ored[wave][o] = po[o];
        th[j0] = th0; th[j0 + 1] = th1;
        if (t0 < DD && t + 1 < TT) xs[t0] = x[(size_t)(b * TT + t + 1) * DD + t0];
        __syncthreads();
        if (t0 < OO) {
            float s = 0.f;
#pragma unroll
            for (int ww = 0; ww < 8; ++ww) s += ored[ww][t0];
            out_o[((size_t)b * TT + t) * OO + t0] = s;
        }
    }
}

extern "C" void kernel_launch(void* const* d_in, const int* in_sizes, int n_in,
                              void* d_out, int out_size, void* d_ws, size_t ws_size,
                              hipStream_t stream) {
    const float* x    = (const float*)d_in[0];
    const float* h0   = (const float*)d_in[1];
    const float* Wi2h = (const float*)d_in[2];
    const float* Wh2h = (const float*)d_in[3];
    const float* Wh2o = (const float*)d_in[4];

    float* out_o = (float*)d_out;                    // [64][1000][8]
    float* out_h = out_o + (size_t)BB * TT * OO;     // [64][1000][1024]

    const size_t XP_BYTES   = (size_t)BB * TT * HH * sizeof(float);            // 262 MB
    const size_t TH_BYTES   = (size_t)2 * NGRP * GB * HH * sizeof(float);      // 512 KB
    const size_t FLG1_BYTES = (size_t)2 * NGRP * 32 * 16 * sizeof(unsigned);   // 64 KB
    const size_t FLG2_BYTES = (size_t)2 * NGRP * 16 * 16 * sizeof(unsigned);   // 32 KB

    int occ1 = 0, occ0 = 0;
    (void)hipOccupancyMaxActiveBlocksPerMultiprocessor(
        &occ1, reinterpret_cast<const void*>(&rnn_sj32<1>), NTH, 0);
    (void)hipOccupancyMaxActiveBlocksPerMultiprocessor(
        &occ0, reinterpret_cast<const void*>(&rnn_sj32<0>), NTH, 0);

    if (ws_size >= XP_BYTES + TH_BYTES + FLG1_BYTES && occ1 >= 2) {
        float*    xp  = (float*)d_ws;
        float*    TH  = (float*)((char*)d_ws + XP_BYTES);
        unsigned* flg = (unsigned*)((char*)d_ws + XP_BYTES + TH_BYTES);
        hipMemsetAsync(flg, 0, FLG1_BYTES, stream);
        xproj_kernel<<<512, 256, 0, stream>>>(x, Wi2h, xp);
        rnn_sj32<1><<<512, NTH, 0, stream>>>(x, h0, Wi2h, Wh2h, xp, out_h, TH, flg);
        h2o_kernel<<<2048, 256, 0, stream>>>(out_h, Wh2o, out_o);
    } else if (ws_size >= TH_BYTES + FLG1_BYTES && occ0 >= 2) {
        float*    TH  = (float*)d_ws;
        unsigned* flg = (unsigned*)((char*)d_ws + TH_BYTES);
        hipMemsetAsync(flg, 0, FLG1_BYTES, stream);
        rnn_sj32<0><<<512, NTH, 0, stream>>>(x, h0, Wi2h, Wh2h, (const float*)d_ws,
                                             out_h, TH, flg);
        h2o_kernel<<<2048, 256, 0, stream>>>(out_h, Wh2o, out_o);
    } else if (ws_size >= TH_BYTES + FLG2_BYTES) {
        float*    TH  = (float*)d_ws;
        unsigned* flg = (unsigned*)((char*)d_ws + TH_BYTES);
        hipMemsetAsync(flg, 0, FLG2_BYTES, stream);
        rnn_coop_t2<<<256, NTH, 0, stream>>>(x, h0, Wi2h, Wh2h, out_h, TH, flg);
        h2o_kernel<<<2048, 256, 0, stream>>>(out_h, Wh2o, out_o);
    } else {
        rnn_fallback<<<BB, 512, 0, stream>>>(x, h0, Wi2h, Wh2h, Wh2o, out_o, out_h);
    }
}